// Round 1
// baseline (563.441 us; speedup 1.0000x reference)
//
#include <hip/hip_runtime.h>

#define DI __device__ __forceinline__

constexpr int AEV = 384;
constexpr int H1N = 160;
constexpr int H2N = 128;
constexpr int H3N = 96;
constexpr int NSP = 4;
constexpr int TM  = 128;   // atoms per block
constexpr int SP1 = 168;   // H1 row stride (elems, +8 pad)
constexpr int SP2 = 136;   // H2 row stride
constexpr int SP3 = 104;   // H3 row stride
constexpr int KP  = 104;   // W-chunk row stride (max chunk 96 + 8 pad)

using short8  = __attribute__((ext_vector_type(8))) short;
using short4v = __attribute__((ext_vector_type(4))) short;
using f32x4   = __attribute__((ext_vector_type(4))) float;

// Pre-transposed bf16 hi/lo weight copies, [species][neuron][k]
__device__ short g_w1h[NSP * H1N * AEV];
__device__ short g_w1l[NSP * H1N * AEV];
__device__ short g_w2h[NSP * H2N * H1N];
__device__ short g_w2l[NSP * H2N * H1N];
__device__ short g_w3h[NSP * H3N * H2N];
__device__ short g_w3l[NSP * H3N * H2N];

DI short f2bf(float f) {                       // RTE fp32 -> bf16
  unsigned u = __float_as_uint(f);
  u += 0x7fffu + ((u >> 16) & 1u);
  return (short)(u >> 16);
}
DI float bf2f(short h) {
  return __uint_as_float(((unsigned)(unsigned short)h) << 16);
}
DI float celu_f(float x) {                     // celu(x,0.1) = max(x,0)+0.1*(exp(min(x,0)/0.1)-1)
  return fmaxf(x, 0.f) + 0.1f * (exp2f(fminf(x, 0.f) * 14.426950408889634f) - 1.f);
}
DI f32x4 mfma16(short8 a, short8 b, f32x4 c) {
  return __builtin_amdgcn_mfma_f32_16x16x32_bf16(a, b, c, 0, 0, 0);
}

// Transpose + hi/lo-split weights: src [s][k][n] fp32 -> dst [s][n][k] bf16 (hi, lo)
__global__ void wt_build(const float* __restrict__ src, int which, int K, int N) {
  short* dh = (which == 0) ? g_w1h : (which == 1) ? g_w2h : g_w3h;
  short* dl = (which == 0) ? g_w1l : (which == 1) ? g_w2l : g_w3l;
  int id = blockIdx.x * 256 + threadIdx.x;
  int per = K * N;
  if (id >= NSP * per) return;
  int s = id / per, r = id - s * per;
  int n = r / K, k = r - n * K;
  float v = src[s * per + k * N + n];
  short h = f2bf(v);
  dh[s * per + n * K + k] = h;
  dl[s * per + n * K + k] = f2bf(v - bf2f(h));
}

// Layers 2/3: B-activations from LDS. MT = #16-neuron tiles, K = input dim.
template <int MT, int K>
DI void layer_lds(const short* __restrict__ wtH, const short* __restrict__ wtL,
                  const short* Hsrc, int SPs, short* Hdst, int SPd,
                  const float* biasL, short* WTb,
                  int tid, int l15, int quad, int wav) {
  constexpr int N = MT * 16;
  f32x4 acc[MT][2];
#pragma unroll
  for (int m = 0; m < MT; ++m)
#pragma unroll
    for (int nt = 0; nt < 2; ++nt)
#pragma unroll
      for (int i = 0; i < 4; ++i) acc[m][nt][i] = 0.f;

#pragma unroll
  for (int c = 0; c < 2; ++c) {
    const int Kc  = (c == 0) ? 96 : (K - 96);
    const int kc0 = (c == 0) ? 0 : 96;
    const int CH  = Kc / 8;
    const int ITERS = (2 * N * CH) / 256;   // exact multiples by construction
    short8 wreg[12];
#pragma unroll
    for (int ii = 0; ii < ITERS; ++ii) {    // global loads BEFORE barrier
      int i = ii * 256 + tid;
      int c16 = i % CH; int t2 = i / CH; int n = t2 % N; int pol = t2 / N;
      wreg[ii] = *(const short8*)((pol ? wtL : wtH) + n * K + kc0 + c16 * 8);
    }
    __syncthreads();                         // prior WTb readers done
#pragma unroll
    for (int ii = 0; ii < ITERS; ++ii) {
      int i = ii * 256 + tid;
      int c16 = i % CH; int t2 = i / CH; int n = t2 % N; int pol = t2 / N;
      *(short8*)(WTb + pol * (N * KP) + n * KP + c16 * 8) = wreg[ii];
    }
    __syncthreads();
    const int nks = Kc / 32;
    for (int ks = 0; ks < nks; ++ks) {
      const int kl = ks * 32 + quad * 8;
      short8 b[2];
#pragma unroll
      for (int nt = 0; nt < 2; ++nt)
        b[nt] = *(const short8*)(Hsrc + (wav * 32 + nt * 16 + l15) * SPs + kc0 + kl);
#pragma unroll
      for (int mt = 0; mt < MT; ++mt) {
        short8 ah = *(const short8*)(WTb + (mt * 16 + l15) * KP + kl);
        short8 al = *(const short8*)(WTb + N * KP + (mt * 16 + l15) * KP + kl);
#pragma unroll
        for (int nt = 0; nt < 2; ++nt) {
          acc[mt][nt] = mfma16(ah, b[nt], acc[mt][nt]);
          acc[mt][nt] = mfma16(al, b[nt], acc[mt][nt]);
        }
      }
    }
  }
  // epilogue: bias + celu + bf16, D^T C-layout -> row-major [atom][neuron], b64 writes
#pragma unroll
  for (int mt = 0; mt < MT; ++mt)
#pragma unroll
    for (int nt = 0; nt < 2; ++nt) {
      int nb = mt * 16 + quad * 4;
      int atom = wav * 32 + nt * 16 + l15;
      short4v o;
#pragma unroll
      for (int j = 0; j < 4; ++j) o[j] = f2bf(celu_f(acc[mt][nt][j] + biasL[nb + j]));
      *(short4v*)(Hdst + atom * SPd + nb) = o;
    }
}

__global__ __launch_bounds__(256, 1) void fused_mlp(
    const float* __restrict__ aev,
    const float* __restrict__ b1, const float* __restrict__ b2,
    const float* __restrict__ b3,
    const float* __restrict__ W4, const float* __restrict__ pb4,
    const int* __restrict__ i0, const int* __restrict__ i1,
    const int* __restrict__ i2, const int* __restrict__ i3,
    int chunk, float* __restrict__ out) {
  __shared__ short WTb[2 * H1N * KP];   // 66560 B
  __shared__ short H1s[TM * SP1];       // 43008 B  (also reused as H3, stride SP3)
  __shared__ short H2s[TM * SP2];       // 34816 B
  __shared__ float BIAS1[H1N];
  __shared__ float BIAS2[H2N];
  __shared__ float BIAS3[H3N];
  __shared__ float RED[4];

  const int tid  = threadIdx.x;
  const int lane = tid & 63, wav = tid >> 6;
  const int l15  = lane & 15, quad = lane >> 4;       // MFMA 16x16x32 lane decomposition
  const int s    = blockIdx.y;
  const int tile = blockIdx.x;
  const int* idx = (s == 0) ? i0 : (s == 1) ? i1 : (s == 2) ? i2 : i3;

  if (tid < H1N) BIAS1[tid] = b1[s * H1N + tid];
  if (tid < H2N) BIAS2[tid] = b2[s * H2N + tid];
  if (tid < H3N) BIAS3[tid] = b3[s * H3N + tid];

  const short* w1h = g_w1h + s * H1N * AEV; const short* w1l = g_w1l + s * H1N * AEV;
  const short* w2h = g_w2h + s * H2N * H1N; const short* w2l = g_w2l + s * H2N * H1N;
  const short* w3h = g_w3h + s * H3N * H2N; const short* w3l = g_w3l + s * H3N * H2N;

  // per-lane gather rows for its two 16-atom column tiles
  const int a0 = tile * TM + wav * 32 + l15;
  const int a1 = a0 + 16;
  const int r0 = idx[a0 < chunk ? a0 : (chunk - 1)];
  const int r1 = idx[a1 < chunk ? a1 : (chunk - 1)];
  const float* xrow0 = aev + (size_t)r0 * AEV + quad * 8;
  const float* xrow1 = aev + (size_t)r1 * AEV + quad * 8;

  // ---------------- Layer 1: H1^T = celu(W1^T X^T + b1), B gathered from global
  f32x4 acc[10][2];
#pragma unroll
  for (int m = 0; m < 10; ++m)
#pragma unroll
    for (int nt = 0; nt < 2; ++nt)
#pragma unroll
      for (int i = 0; i < 4; ++i) acc[m][nt][i] = 0.f;

#pragma unroll
  for (int c = 0; c < 4; ++c) {
    const int kc0 = c * 96;
    float4 xg[3][2][2];
#pragma unroll
    for (int ks = 0; ks < 3; ++ks)
#pragma unroll
      for (int nt = 0; nt < 2; ++nt) {
        const float* p = (nt ? xrow1 : xrow0) + kc0 + ks * 32;
        xg[ks][nt][0] = *(const float4*)p;
        xg[ks][nt][1] = *(const float4*)(p + 4);
      }
    short8 wreg[15];
#pragma unroll
    for (int ii = 0; ii < 15; ++ii) {
      int i = ii * 256 + tid;
      int c16 = i % 12; int t2 = i / 12; int n = t2 % H1N; int pol = t2 / H1N;
      wreg[ii] = *(const short8*)((pol ? w1l : w1h) + n * AEV + kc0 + c16 * 8);
    }
    __syncthreads();
#pragma unroll
    for (int ii = 0; ii < 15; ++ii) {
      int i = ii * 256 + tid;
      int c16 = i % 12; int t2 = i / 12; int n = t2 % H1N; int pol = t2 / H1N;
      *(short8*)(WTb + pol * (H1N * KP) + n * KP + c16 * 8) = wreg[ii];
    }
    __syncthreads();
#pragma unroll
    for (int ks = 0; ks < 3; ++ks) {
      short8 b[2];
#pragma unroll
      for (int nt = 0; nt < 2; ++nt) {
        float4 A = xg[ks][nt][0], B = xg[ks][nt][1];
        short8 t;
        t[0] = f2bf(A.x); t[1] = f2bf(A.y); t[2] = f2bf(A.z); t[3] = f2bf(A.w);
        t[4] = f2bf(B.x); t[5] = f2bf(B.y); t[6] = f2bf(B.z); t[7] = f2bf(B.w);
        b[nt] = t;
      }
      const int kl = ks * 32 + quad * 8;
#pragma unroll
      for (int mt = 0; mt < 10; ++mt) {
        short8 ah = *(const short8*)(WTb + (mt * 16 + l15) * KP + kl);
        short8 al = *(const short8*)(WTb + H1N * KP + (mt * 16 + l15) * KP + kl);
#pragma unroll
        for (int nt = 0; nt < 2; ++nt) {
          acc[mt][nt] = mfma16(ah, b[nt], acc[mt][nt]);
          acc[mt][nt] = mfma16(al, b[nt], acc[mt][nt]);
        }
      }
    }
  }
#pragma unroll
  for (int mt = 0; mt < 10; ++mt)
#pragma unroll
    for (int nt = 0; nt < 2; ++nt) {
      int nb = mt * 16 + quad * 4;
      int atom = wav * 32 + nt * 16 + l15;
      short4v o;
#pragma unroll
      for (int j = 0; j < 4; ++j) o[j] = f2bf(celu_f(acc[mt][nt][j] + BIAS1[nb + j]));
      *(short4v*)(H1s + atom * SP1 + nb) = o;
    }

  // ---------------- Layers 2 and 3 (H3 aliases the H1 buffer)
  layer_lds<8, 160>(w2h, w2l, H1s, SP1, H2s, SP2, BIAS2, WTb, tid, l15, quad, wav);
  layer_lds<6, 128>(w3h, w3l, H2s, SP2, H1s, SP3, BIAS3, WTb, tid, l15, quad, wav);
  __syncthreads();

  // ---------------- Layer 4: per-atom dot(H3, w4) + b4, then block reduce
  float e = 0.f;
  if (tid < TM) {
    const short* h3 = H1s + tid * SP3;
    const float* w4 = W4 + s * H3N;
    float sum = 0.f;
#pragma unroll
    for (int j = 0; j < H3N; ++j) sum += bf2f(h3[j]) * w4[j];
    if (tile * TM + tid < chunk) e = sum + pb4[s];
  }
#pragma unroll
  for (int off = 32; off > 0; off >>= 1) e += __shfl_down(e, off, 64);
  if (lane == 0) RED[wav] = e;
  __syncthreads();
  if (tid == 0) atomicAdd(out, RED[0] + RED[1] + RED[2] + RED[3]);
}

extern "C" void kernel_launch(void* const* d_in, const int* in_sizes, int n_in,
                              void* d_out, int out_size, void* d_ws, size_t ws_size,
                              hipStream_t stream) {
  (void)n_in; (void)d_ws; (void)ws_size;
  const float* aev = (const float*)d_in[0];
  const float* W1  = (const float*)d_in[1];
  const float* b1  = (const float*)d_in[2];
  const float* W2  = (const float*)d_in[3];
  const float* b2  = (const float*)d_in[4];
  const float* W3  = (const float*)d_in[5];
  const float* b3  = (const float*)d_in[6];
  const float* W4  = (const float*)d_in[7];
  const float* b4  = (const float*)d_in[8];
  const int* iH = (const int*)d_in[9];
  const int* iC = (const int*)d_in[10];
  const int* iN = (const int*)d_in[11];
  const int* iO = (const int*)d_in[12];
  const int chunk = in_sizes[9];

  hipMemsetAsync(d_out, 0, out_size * sizeof(float), stream);
  wt_build<<<(NSP * AEV * H1N + 255) / 256, 256, 0, stream>>>(W1, 0, AEV, H1N);
  wt_build<<<(NSP * H1N * H2N + 255) / 256, 256, 0, stream>>>(W2, 1, H1N, H2N);
  wt_build<<<(NSP * H2N * H3N + 255) / 256, 256, 0, stream>>>(W3, 2, H2N, H3N);

  const int tiles = (chunk + TM - 1) / TM;
  dim3 grid(tiles, NSP);
  fused_mlp<<<grid, 256, 0, stream>>>(aev, b1, b2, b3, W4, b4,
                                      iH, iC, iN, iO, chunk, (float*)d_out);
}